// Round 2
// baseline (527.868 us; speedup 1.0000x reference)
//
#include <hip/hip_runtime.h>
#include <hip/hip_bf16.h>

#define B_ 2
#define C_ 256
#define N_ 110592
#define CN_ ((size_t)C_ * N_)

typedef __attribute__((ext_vector_type(4))) float f32x4;
typedef __attribute__((ext_vector_type(2))) float f32x2;
typedef __attribute__((ext_vector_type(8))) short bf16x8;
typedef __attribute__((ext_vector_type(4))) short bf16x4;

__device__ __forceinline__ short f2bf(float f) {
    union { float f; unsigned u; } v; v.f = f;
    unsigned r = (v.u + 0x7fffu + ((v.u >> 16) & 1u)) >> 16;
    return (short)(r & 0xffffu);
}

// ---------------- Pass 1: raw Gram (split-K) + rowsums, 2-phase pipelined --
// grid (nck, B), 512 threads. LDS: 2 x (256ch x 64n bf16) = 64 KB.
__global__ __launch_bounds__(512) void k_gram(
        const float* __restrict__ x, float* __restrict__ part,
        float* __restrict__ rspart, int T, int nck) {
    __shared__ short Xs[2 * 256 * 64];
    __shared__ float rs_s[256];
    const int t = threadIdx.x;
    const int lane = t & 63, wave = t >> 6;
    const int chunk = blockIdx.x, b = blockIdx.y;
    const int k0 = chunk * T * 64;
    const int s4 = t & 15;
    const int crow0 = t >> 4;            // c for rep i is i*32 + crow0

    f32x4 acc[4][8];
#pragma unroll
    for (int i = 0; i < 4; ++i)
#pragma unroll
        for (int j = 0; j < 8; ++j) acc[i][j] = f32x4{0.f, 0.f, 0.f, 0.f};
    float rs[8];
#pragma unroll
    for (int i = 0; i < 8; ++i) rs[i] = 0.f;

    const int cw0 = (wave & 3) * 64;
    const int dw0 = (wave >> 2) * 128;
    const int r16 = lane & 15, g16 = lane >> 4;
    const float* xb = x + (size_t)b * CN_;

    f32x4 va[8], vb[8];
#pragma unroll
    for (int i = 0; i < 8; ++i)
        va[i] = *(const f32x4*)(xb + (size_t)(i * 32 + crow0) * N_ + k0 + s4 * 4);

#define GSTEP(TT, BUF, VC, VN)                                                  \
    {                                                                           \
        _Pragma("unroll")                                                       \
        for (int i = 0; i < 8; ++i) {                                           \
            f32x4 v = VC[i];                                                    \
            rs[i] += (v.x + v.y) + (v.z + v.w);                                 \
            bf16x4 h;                                                           \
            h.x = f2bf(v.x); h.y = f2bf(v.y); h.z = f2bf(v.z); h.w = f2bf(v.w); \
            int c = i * 32 + crow0;                                             \
            *(bf16x4*)((char*)Xs + (BUF)*32768 +                                \
                ((c * 128 + s4 * 8) ^ ((c & 7) << 4))) = h;                     \
        }                                                                       \
        __syncthreads();                                                        \
        if ((TT) + 1 < T) {                                                     \
            _Pragma("unroll")                                                   \
            for (int i = 0; i < 8; ++i)                                         \
                VN[i] = *(const f32x4*)(xb + (size_t)(i * 32 + crow0) * N_ +    \
                                        k0 + ((TT) + 1) * 64 + s4 * 4);         \
        }                                                                       \
        _Pragma("unroll")                                                       \
        for (int k2 = 0; k2 < 2; ++k2) {                                        \
            bf16x8 afr[4];                                                      \
            _Pragma("unroll")                                                   \
            for (int ct = 0; ct < 4; ++ct) {                                    \
                int row = cw0 + ct * 16 + r16;                                  \
                afr[ct] = *(const bf16x8*)((const char*)Xs + (BUF)*32768 +      \
                    ((row * 128 + k2 * 64 + g16 * 16) ^ ((row & 7) << 4)));     \
            }                                                                   \
            _Pragma("unroll")                                                   \
            for (int dt = 0; dt < 8; ++dt) {                                    \
                int row = dw0 + dt * 16 + r16;                                  \
                bf16x8 bfr = *(const bf16x8*)((const char*)Xs + (BUF)*32768 +   \
                    ((row * 128 + k2 * 64 + g16 * 16) ^ ((row & 7) << 4)));     \
                _Pragma("unroll")                                               \
                for (int ct = 0; ct < 4; ++ct)                                  \
                    acc[ct][dt] = __builtin_amdgcn_mfma_f32_16x16x32_bf16(      \
                        afr[ct], bfr, acc[ct][dt], 0, 0, 0);                    \
            }                                                                   \
        }                                                                       \
    }

    for (int tt = 0; tt < T; tt += 2) {
        GSTEP(tt, 0, va, vb);
        GSTEP(tt + 1, 1, vb, va);
    }
#undef GSTEP

    // rowsum reduce: 16 lanes share each c (c = i*32 + crow0)
#pragma unroll
    for (int i = 0; i < 8; ++i) {
        float r = rs[i];
        r += __shfl_xor(r, 1);
        r += __shfl_xor(r, 2);
        r += __shfl_xor(r, 4);
        r += __shfl_xor(r, 8);
        if ((t & 15) == 0) rs_s[i * 32 + crow0] = r;
    }
    __syncthreads();
    if (t < 256) rspart[((size_t)b * nck + chunk) * C_ + t] = rs_s[t];

    float* pp = part + ((size_t)b * nck + chunk) * (C_ * C_);
#pragma unroll
    for (int ct = 0; ct < 4; ++ct)
#pragma unroll
        for (int dt = 0; dt < 8; ++dt) {
            int d = dw0 + dt * 16 + r16;
#pragma unroll
            for (int rr = 0; rr < 4; ++rr) {
                int c = cw0 + ct * 16 + g16 * 4 + rr;
                pp[(size_t)c * C_ + d] = acc[ct][dt][rr];
            }
        }
}

// ---------------- reduce partial Grams ----------------
__global__ void k_reduce(const float* __restrict__ part, float* __restrict__ Graw,
                         int nck) {
    int bid = blockIdx.x;
    int b = bid >> 8, c = bid & 255;
    int d = threadIdx.x;
    float s = 0.f;
    for (int p = 0; p < nck; ++p)
        s += part[(((size_t)b * nck + p) * (C_ * C_)) + (size_t)c * C_ + d];
    Graw[((size_t)b * C_ + c) * C_ + d] = s;
}

// ---------------- stats ----------------
__global__ void k_stats(const float* __restrict__ rspart, const float* __restrict__ Graw,
                        float* __restrict__ mean, float* __restrict__ rsig, int nck) {
    int t = threadIdx.x;
    int b = t >> 8, c = t & 255;
    float s = 0.f;
    for (int p = 0; p < nck; ++p) s += rspart[((size_t)b * nck + p) * C_ + c];
    float m = s / (float)N_;
    float g = Graw[((size_t)b * C_ + c) * C_ + c];
    float var = g / (float)N_ - m * m;
    mean[t] = m;
    rsig[t] = rsqrtf(var + 1e-5f);
}

// ---------------- P = Wq * Gn ----------------
__global__ void k_gemm1(const float* __restrict__ Wq, const float* __restrict__ Graw,
                        const float* __restrict__ mean, const float* __restrict__ rsig,
                        float* __restrict__ P) {
    int bid = blockIdx.x; int b = bid >> 8, c = bid & 255; int d = threadIdx.x;
    const float* G = Graw + (size_t)b * C_ * C_;
    const float* mb = mean + b * C_;
    const float* rb = rsig + b * C_;
    float md = mb[d], rd = rb[d];
    float a1 = 0.f, a2 = 0.f;
    for (int e = 0; e < C_; ++e) {
        float w = Wq[(size_t)c * C_ + e] * rb[e];
        a1 += w * G[(size_t)e * C_ + d];
        a2 += w * mb[e];
    }
    P[((size_t)b * C_ + c) * C_ + d] = rd * a1 - (float)N_ * md * rd * a2;
}

// ---------------- atten = softmax(P*Wk^T + N bq bk^T)/16 + outer/16 --------
__global__ void k_attn(const float* __restrict__ P, const float* __restrict__ Wk,
                       const float* __restrict__ bq, const float* __restrict__ bk,
                       const float* __restrict__ outer, float* __restrict__ atten) {
    __shared__ float Pr_s[256];
    __shared__ float red[8];
    int bid = blockIdx.x; int b = bid >> 8, c = bid & 255; int d = threadIdx.x;
    int lane = d & 63, w = d >> 6;
    Pr_s[d] = P[((size_t)b * C_ + c) * C_ + d];
    __syncthreads();
    float a = 0.f;
#pragma unroll 4
    for (int e4 = 0; e4 < 64; ++e4) {
        f32x4 wv = *(const f32x4*)(Wk + (size_t)d * C_ + e4 * 4);
        f32x4 pv = *(const f32x4*)(Pr_s + e4 * 4);
        a += wv.x * pv.x + wv.y * pv.y + wv.z * pv.z + wv.w * pv.w;
    }
    float v = a + (float)N_ * bq[c] * bk[d];
    float m = v;
    for (int off = 32; off; off >>= 1) m = fmaxf(m, __shfl_xor(m, off));
    if (lane == 0) red[w] = m;
    __syncthreads();
    m = fmaxf(fmaxf(red[0], red[1]), fmaxf(red[2], red[3]));
    float e = __expf(v - m);
    float s = e;
    for (int off = 32; off; off >>= 1) s += __shfl_xor(s, off);
    if (lane == 0) red[4 + w] = s;
    __syncthreads();
    s = red[4] + red[5] + red[6] + red[7];
    atten[((size_t)b * C_ + c) * C_ + d] = e / (s * 16.f) + outer[(size_t)c * C_ + d] * 0.0625f;
}

// ---------------- A = (atten*Wv + I)*diag(rsig) in FRAGMENT layout, beta ---
// Abf index: ((k>>3)*256 + c)*8 + (k&7)  (k = column of A = channel)
__global__ void k_gemm3(const float* __restrict__ atten, const float* __restrict__ Wv,
                        const float* __restrict__ bv, const float* __restrict__ mean,
                        const float* __restrict__ rsig, short* __restrict__ Abf,
                        float* __restrict__ beta) {
    __shared__ float red[4];
    int bid = blockIdx.x; int b = bid >> 8, c = bid & 255; int g = threadIdx.x;
    int lane = g & 63, w = g >> 6;
    const float* at = atten + ((size_t)b * C_ + c) * C_;
    float a = 0.f;
    for (int d = 0; d < C_; ++d)
        a += at[d] * Wv[(size_t)d * C_ + g];
    float Ag = (a + ((g == c) ? 1.f : 0.f)) * rsig[b * C_ + g];
    Abf[(size_t)b * C_ * C_ + ((size_t)(g >> 3) * C_ + c) * 8 + (g & 7)] = f2bf(Ag);
    float u = at[g] * bv[g] - Ag * mean[b * C_ + g];
    for (int off = 32; off; off >>= 1) u += __shfl_xor(u, off);
    if (lane == 0) red[w] = u;
    __syncthreads();
    if (g == 0) beta[b * C_ + c] = red[0] + red[1] + red[2] + red[3];
}

// ---------------- Pass 2: out = A * x + beta, 2-phase pipelined ------------
// grid (N/256, B), 512 threads. A read from global (L1-resident slices);
// x reg-staged -> XOR-swizzled fragment-layout LDS tile (2 x 16 KB).
#define SWZ(bb) ((bb) ^ ((((bb) >> 8) & 7) << 4))
__global__ __launch_bounds__(512) void k_out(
        const float* __restrict__ x, const short* __restrict__ Abf,
        const float* __restrict__ beta, float* __restrict__ out) {
    __shared__ short Xs[2 * 8192];     // 2 x 16 KB
    __shared__ float beta_s[256];
    const int t = threadIdx.x, lane = t & 63, wave = t >> 6;
    const int nb = blockIdx.x, b = blockIdx.y;
    const int nb0 = nb * 256;
    if (t < 256) beta_s[t] = beta[b * C_ + t];
    const short* Ab = Abf + (size_t)b * C_ * C_;
    const float* xb = x + (size_t)b * CN_;
    float* ob = out + (size_t)b * CN_;
    const int col = lane & 15, g16 = lane >> 4;
    const int kg = t >> 7, nn = (t & 127) * 2;

    f32x4 acc[16][2];
#pragma unroll
    for (int i = 0; i < 16; ++i) {
        acc[i][0] = f32x4{0.f, 0.f, 0.f, 0.f};
        acc[i][1] = f32x4{0.f, 0.f, 0.f, 0.f};
    }

    f32x2 va[8], vb[8];
#pragma unroll
    for (int j = 0; j < 8; ++j)
        va[j] = *(const f32x2*)(xb + (size_t)(kg * 8 + j) * N_ + nb0 + nn);

#define OSTEP(KS, BUF, VC, VN)                                                  \
    {                                                                           \
        bf16x8 w0, w1;                                                          \
        _Pragma("unroll")                                                       \
        for (int j = 0; j < 8; ++j) { w0[j] = f2bf(VC[j].x); w1[j] = f2bf(VC[j].y); } \
        int base = (kg * 256 + nn) * 16;                                        \
        *(bf16x8*)((char*)Xs + (BUF)*16384 + SWZ(base)) = w0;                   \
        *(bf16x8*)((char*)Xs + (BUF)*16384 + SWZ(base + 16)) = w1;              \
        __syncthreads();                                                        \
        if ((KS) + 1 < 8) {                                                     \
            _Pragma("unroll")                                                   \
            for (int j = 0; j < 8; ++j)                                         \
                VN[j] = *(const f32x2*)(xb + (size_t)(((KS) + 1) * 32 + kg * 8 + j) * N_ + nb0 + nn); \
        }                                                                       \
        int rb0 = (g16 * 256 + wave * 32 + col) * 16;                           \
        bf16x8 xf0 = *(const bf16x8*)((const char*)Xs + (BUF)*16384 + SWZ(rb0));        \
        bf16x8 xf1 = *(const bf16x8*)((const char*)Xs + (BUF)*16384 + SWZ(rb0 + 256));  \
        _Pragma("unroll")                                                       \
        for (int ct = 0; ct < 16; ++ct) {                                       \
            bf16x8 afr = *(const bf16x8*)(Ab + (((KS)*4 + g16) * 256 + ct * 16 + col) * 8); \
            acc[ct][0] = __builtin_amdgcn_mfma_f32_16x16x32_bf16(afr, xf0, acc[ct][0], 0, 0, 0); \
            acc[ct][1] = __builtin_amdgcn_mfma_f32_16x16x32_bf16(afr, xf1, acc[ct][1], 0, 0, 0); \
        }                                                                       \
    }

    for (int ks = 0; ks < 8; ks += 2) {
        OSTEP(ks, 0, va, vb);
        OSTEP(ks + 1, 1, vb, va);
    }
#undef OSTEP

#pragma unroll
    for (int ct = 0; ct < 16; ++ct)
#pragma unroll
        for (int nt = 0; nt < 2; ++nt) {
            int n = nb0 + wave * 32 + nt * 16 + col;
#pragma unroll
            for (int rr = 0; rr < 4; ++rr) {
                int c = ct * 16 + g16 * 4 + rr;
                ob[(size_t)c * N_ + n] = acc[ct][nt][rr] + beta_s[c];
            }
        }
}

extern "C" void kernel_launch(void* const* d_in, const int* in_sizes, int n_in,
                              void* d_out, int out_size, void* d_ws, size_t ws_size,
                              hipStream_t stream) {
    (void)in_sizes; (void)n_in; (void)out_size;
    const float* x     = (const float*)d_in[0];
    const float* Wq    = (const float*)d_in[1];
    const float* bq    = (const float*)d_in[2];
    const float* Wk    = (const float*)d_in[3];
    const float* bk    = (const float*)d_in[4];
    const float* Wv    = (const float*)d_in[5];
    const float* bv    = (const float*)d_in[6];
    const float* outer = (const float*)d_in[7];
    float* out = (float*)d_out;

    char* w = (char*)d_ws;
    float* mean   = (float*)(w);
    float* rsig   = (float*)(w + 2048);
    float* beta   = (float*)(w + 4096);
    float* Graw   = (float*)(w + 8192);
    float* P      = (float*)(w + 8192 + 1 * 524288);
    float* atten  = (float*)(w + 8192 + 2 * 524288);
    short* Abf    = (short*)(w + 8192 + 3 * 524288);
    float* rspart = (float*)(w + 8192 + 3 * 524288 + 262144);
    char*  partc  = (w + 8192 + 3 * 524288 + 262144 + 442368);
    float* part   = (float*)partc;
    size_t fixed  = 8192 + 3 * 524288 + 262144 + 442368;

    // choose nck among exact divisors of 1728 (tiles of 64), largest fitting ws
    const int cand[6] = {216, 144, 108, 96, 72, 54};
    int nck = 54;
    for (int i = 0; i < 6; ++i) {
        if (fixed + (size_t)cand[i] * B_ * C_ * C_ * 4 <= ws_size) { nck = cand[i]; break; }
    }
    int T = (N_ / 64) / nck;   // tiles per block (even for all candidates)

    k_gram  <<<dim3(nck, B_), 512, 0, stream>>>(x, part, rspart, T, nck);
    k_reduce<<<dim3(B_ * C_), 256, 0, stream>>>(part, Graw, nck);
    k_stats <<<dim3(1), 512, 0, stream>>>(rspart, Graw, mean, rsig, nck);
    k_gemm1 <<<dim3(B_ * C_), C_, 0, stream>>>(Wq, Graw, mean, rsig, P);
    k_attn  <<<dim3(B_ * C_), C_, 0, stream>>>(P, Wk, bq, bk, outer, atten);
    k_gemm3 <<<dim3(B_ * C_), C_, 0, stream>>>(atten, Wv, bv, mean, rsig, Abf, beta);
    k_out   <<<dim3(N_ / 256, B_), 512, 0, stream>>>(x, Abf, beta, out);
}

// Round 3
// 361.390 us; speedup vs baseline: 1.4607x; 1.4607x over previous
//
#include <hip/hip_runtime.h>
#include <hip/hip_bf16.h>

#define B_ 2
#define C_ 256
#define N_ 110592
#define CN_ ((size_t)C_ * N_)
#define NCK_ 108          // K-chunks in gram (divides 1728)
#define T_ 16             // 64-col tiles per chunk: 108*16*64 = 110592

typedef __attribute__((ext_vector_type(4))) float f32x4;
typedef __attribute__((ext_vector_type(8))) short bf16x8;
typedef __attribute__((ext_vector_type(4))) short bf16x4;

__device__ __forceinline__ short f2bf(float f) {
    union { float f; unsigned u; } v; v.f = f;
    unsigned r = (v.u + 0x7fffu + ((v.u >> 16) & 1u)) >> 16;
    return (short)(r & 0xffffu);
}

// ---------------- Pass 1: raw Gram (split-K) + rowsums -------------------
// 1024 thr / 16 waves, wave-tile 64x64 (acc=64/lane). 2-phase reg-staged
// pipeline, LDS pitch 144B (bank-conflict-free), one barrier per tile.
__global__ __launch_bounds__(1024) void k_gram(
        const float* __restrict__ x, float* __restrict__ part,
        float* __restrict__ rspart) {
    __shared__ short Xs[2 * 256 * 72];   // 2 buffers, 256 rows x 144B pitch
    __shared__ float rs_s[256];
    const int t = threadIdx.x, lane = t & 63, wave = t >> 6;
    const int chunk = blockIdx.x, b = blockIdx.y;
    const int k0 = chunk * (T_ * 64);
    const int f4 = t & 15;               // 16B chunk within row
    const int crow = t >> 4;             // 0..63 ; c = q*64 + crow
    const int cw0 = (wave & 3) * 64, dw0 = (wave >> 2) * 64;
    const int r16 = lane & 15, g16 = lane >> 4;
    const float* xb = x + (size_t)b * CN_;

    f32x4 acc[4][4];
#pragma unroll
    for (int i = 0; i < 4; ++i)
#pragma unroll
        for (int j = 0; j < 4; ++j) acc[i][j] = f32x4{0.f, 0.f, 0.f, 0.f};
    float rs[4] = {0.f, 0.f, 0.f, 0.f};

    f32x4 va[4];
#pragma unroll
    for (int q = 0; q < 4; ++q)
        va[q] = *(const f32x4*)(xb + (size_t)(q * 64 + crow) * N_ + k0 + f4 * 4);

    for (int tt = 0; tt < T_; ++tt) {
        const int buf = (tt & 1) * 18432;          // shorts
        // convert + LDS write + rowsum accumulate
#pragma unroll
        for (int q = 0; q < 4; ++q) {
            f32x4 v = va[q];
            rs[q] += (v.x + v.y) + (v.z + v.w);
            bf16x4 h;
            h.x = f2bf(v.x); h.y = f2bf(v.y); h.z = f2bf(v.z); h.w = f2bf(v.w);
            *(bf16x4*)(Xs + buf + (q * 64 + crow) * 72 + f4 * 4) = h;
        }
        __syncthreads();
        if (tt + 1 < T_) {
#pragma unroll
            for (int q = 0; q < 4; ++q)
                va[q] = *(const f32x4*)(xb + (size_t)(q * 64 + crow) * N_ +
                                        k0 + (tt + 1) * 64 + f4 * 4);
        }
#pragma unroll
        for (int k2 = 0; k2 < 2; ++k2) {
            bf16x8 afr[4];
#pragma unroll
            for (int ct = 0; ct < 4; ++ct)
                afr[ct] = *(const bf16x8*)(Xs + buf + (cw0 + ct * 16 + r16) * 72 +
                                           (k2 * 4 + g16) * 8);
#pragma unroll
            for (int dt = 0; dt < 4; ++dt) {
                bf16x8 bfr = *(const bf16x8*)(Xs + buf + (dw0 + dt * 16 + r16) * 72 +
                                              (k2 * 4 + g16) * 8);
#pragma unroll
                for (int ct = 0; ct < 4; ++ct)
                    acc[ct][dt] = __builtin_amdgcn_mfma_f32_16x16x32_bf16(
                        afr[ct], bfr, acc[ct][dt], 0, 0, 0);
            }
        }
    }

    // rowsums: 16 threads (same t>>4) share each row
#pragma unroll
    for (int q = 0; q < 4; ++q) {
        float r = rs[q];
        r += __shfl_xor(r, 1);
        r += __shfl_xor(r, 2);
        r += __shfl_xor(r, 4);
        r += __shfl_xor(r, 8);
        if ((t & 15) == 0) rs_s[q * 64 + crow] = r;
    }
    __syncthreads();
    if (t < 256) rspart[((size_t)b * NCK_ + chunk) * C_ + t] = rs_s[t];

    float* pp = part + ((size_t)b * NCK_ + chunk) * (C_ * C_);
#pragma unroll
    for (int ct = 0; ct < 4; ++ct)
#pragma unroll
        for (int dt = 0; dt < 4; ++dt) {
            int d = dw0 + dt * 16 + r16;
#pragma unroll
            for (int rr = 0; rr < 4; ++rr) {
                int c = cw0 + ct * 16 + g16 * 4 + rr;
                pp[(size_t)c * C_ + d] = acc[ct][dt][rr];
            }
        }
}

// ------------- reduce partial Grams + fused stats (mean, rsig) -----------
__global__ void k_reduce(const float* __restrict__ part, const float* __restrict__ rspart,
                         float* __restrict__ Graw, float* __restrict__ mean,
                         float* __restrict__ rsig) {
    __shared__ float diag_s;
    __shared__ float red[256];
    int bid = blockIdx.x;
    int b = bid >> 8, c = bid & 255;
    int d = threadIdx.x;
    float s = 0.f;
    for (int p = 0; p < NCK_; ++p)
        s += part[(((size_t)b * NCK_ + p) * (C_ * C_)) + (size_t)c * C_ + d];
    Graw[((size_t)b * C_ + c) * C_ + d] = s;
    if (d == c) diag_s = s;
    // rowsum total for row c
    float rsum = 0.f;
    for (int p = d; p < NCK_; p += 256)
        rsum += rspart[((size_t)b * NCK_ + p) * C_ + c];
    red[d] = rsum;
    __syncthreads();
    if (d < 128) red[d] += red[d + 128];
    __syncthreads();
    if (d < 64) red[d] += red[d + 64];
    __syncthreads();
    if (d == 0) {
        float tot = 0.f;
#pragma unroll
        for (int i = 0; i < 64; ++i) tot += red[i];
        float m = tot / (float)N_;
        float var = diag_s / (float)N_ - m * m;
        mean[b * C_ + c] = m;
        rsig[b * C_ + c] = rsqrtf(var + 1e-5f);
    }
}

// ---------------- P = Wq * Gn ----------------
__global__ void k_gemm1(const float* __restrict__ Wq, const float* __restrict__ Graw,
                        const float* __restrict__ mean, const float* __restrict__ rsig,
                        float* __restrict__ P) {
    int bid = blockIdx.x; int b = bid >> 8, c = bid & 255; int d = threadIdx.x;
    const float* G = Graw + (size_t)b * C_ * C_;
    const float* mb = mean + b * C_;
    const float* rb = rsig + b * C_;
    float md = mb[d], rd = rb[d];
    float a1 = 0.f, a2 = 0.f;
    for (int e = 0; e < C_; ++e) {
        float w = Wq[(size_t)c * C_ + e] * rb[e];
        a1 += w * G[(size_t)e * C_ + d];
        a2 += w * mb[e];
    }
    P[((size_t)b * C_ + c) * C_ + d] = rd * a1 - (float)N_ * md * rd * a2;
}

// ---------------- atten = softmax(P*Wk^T + N bq bk^T)/16 + outer/16 ------
__global__ void k_attn(const float* __restrict__ P, const float* __restrict__ Wk,
                       const float* __restrict__ bq, const float* __restrict__ bk,
                       const float* __restrict__ outer, float* __restrict__ atten) {
    __shared__ float Pr_s[256];
    __shared__ float red[8];
    int bid = blockIdx.x; int b = bid >> 8, c = bid & 255; int d = threadIdx.x;
    int lane = d & 63, w = d >> 6;
    Pr_s[d] = P[((size_t)b * C_ + c) * C_ + d];
    __syncthreads();
    float a = 0.f;
#pragma unroll 4
    for (int e4 = 0; e4 < 64; ++e4) {
        f32x4 wv = *(const f32x4*)(Wk + (size_t)d * C_ + e4 * 4);
        f32x4 pv = *(const f32x4*)(Pr_s + e4 * 4);
        a += wv.x * pv.x + wv.y * pv.y + wv.z * pv.z + wv.w * pv.w;
    }
    float v = a + (float)N_ * bq[c] * bk[d];
    float m = v;
    for (int off = 32; off; off >>= 1) m = fmaxf(m, __shfl_xor(m, off));
    if (lane == 0) red[w] = m;
    __syncthreads();
    m = fmaxf(fmaxf(red[0], red[1]), fmaxf(red[2], red[3]));
    float e = __expf(v - m);
    float s = e;
    for (int off = 32; off; off >>= 1) s += __shfl_xor(s, off);
    if (lane == 0) red[4 + w] = s;
    __syncthreads();
    s = red[4] + red[5] + red[6] + red[7];
    atten[((size_t)b * C_ + c) * C_ + d] = e / (s * 16.f) + outer[(size_t)c * C_ + d] * 0.0625f;
}

// ------------- A = (atten*Wv + I)*diag(rsig) in FRAGMENT layout, beta ----
__global__ void k_gemm3(const float* __restrict__ atten, const float* __restrict__ Wv,
                        const float* __restrict__ bv, const float* __restrict__ mean,
                        const float* __restrict__ rsig, short* __restrict__ Abf,
                        float* __restrict__ beta) {
    __shared__ float red[4];
    int bid = blockIdx.x; int b = bid >> 8, c = bid & 255; int g = threadIdx.x;
    int lane = g & 63, w = g >> 6;
    const float* at = atten + ((size_t)b * C_ + c) * C_;
    float a = 0.f;
    for (int d = 0; d < C_; ++d)
        a += at[d] * Wv[(size_t)d * C_ + g];
    float Ag = (a + ((g == c) ? 1.f : 0.f)) * rsig[b * C_ + g];
    Abf[(size_t)b * C_ * C_ + ((size_t)(g >> 3) * C_ + c) * 8 + (g & 7)] = f2bf(Ag);
    float u = at[g] * bv[g] - Ag * mean[b * C_ + g];
    for (int off = 32; off; off >>= 1) u += __shfl_xor(u, off);
    if (lane == 0) red[w] = u;
    __syncthreads();
    if (g == 0) beta[b * C_ + c] = red[0] + red[1] + red[2] + red[3];
}

// ------------- prep: f32 x -> ch-packed bf16 xf[b][kgrp][n][8] -----------
// block: 64ch x 128n tile, LDS transpose. grid (864, 4, B), 256 thr.
__global__ __launch_bounds__(256) void k_prepf(
        const float* __restrict__ x, short* __restrict__ xf) {
    __shared__ float Xf[64 * 132];
    const int t = threadIdx.x;
    const int n0 = blockIdx.x * 128, ctile = blockIdx.y, b = blockIdx.z;
    const int c0 = ctile * 64;
    const float* xb = x + (size_t)b * CN_;
    short* xfb = xf + (size_t)b * CN_;
#pragma unroll
    for (int i = 0; i < 8; ++i) {
        int row = i * 8 + (t >> 5), f4 = t & 31;
        f32x4 v = *(const f32x4*)(xb + (size_t)(c0 + row) * N_ + n0 + f4 * 4);
        *(f32x4*)(Xf + row * 132 + f4 * 4) = v;
    }
    __syncthreads();
#pragma unroll
    for (int it = 0; it < 4; ++it) {
        int cg = it * 2 + (t >> 7), n = t & 127;
        bf16x8 h;
#pragma unroll
        for (int j = 0; j < 8; ++j)
            h[j] = f2bf(Xf[(cg * 8 + j) * 132 + n]);
        *(bf16x8*)(xfb + ((size_t)(ctile * 8 + cg) * N_ + n0 + n) * 8) = h;
    }
}

// ------------- Pass 2 (main): out = A*x + beta, no LDS -------------------
__global__ __launch_bounds__(512) void k_out_bf(
        const short* __restrict__ xf, const short* __restrict__ Abf,
        const float* __restrict__ beta, float* __restrict__ out) {
    __shared__ float beta_s[256];
    const int t = threadIdx.x, lane = t & 63, wave = t >> 6;
    const int nb = blockIdx.x, b = blockIdx.y;
    const int col = lane & 15, g16 = lane >> 4;
    const int n_w = nb * 256 + wave * 32;
    if (t < 256) beta_s[t] = beta[b * C_ + t];
    __syncthreads();
    const short* Ab = Abf + (size_t)b * C_ * C_;
    const short* xfb = xf + (size_t)b * CN_;
    float* ob = out + (size_t)b * CN_;

    f32x4 acc[16][2];
#pragma unroll
    for (int i = 0; i < 16; ++i) {
        acc[i][0] = f32x4{0.f, 0.f, 0.f, 0.f};
        acc[i][1] = f32x4{0.f, 0.f, 0.f, 0.f};
    }

#define XA(KS, NT) (*(const bf16x8*)(xfb + ((size_t)((KS)*4 + g16) * N_ + n_w + (NT)*16 + col) * 8))
    bf16x8 pfA[2], pfB[2];
    pfA[0] = XA(0, 0); pfB[0] = XA(0, 1);
    pfA[1] = XA(1, 0); pfB[1] = XA(1, 1);
#pragma unroll
    for (int ks = 0; ks < 8; ++ks) {
        bf16x8 xa = pfA[ks & 1], xv = pfB[ks & 1];
        if (ks + 2 < 8) { pfA[ks & 1] = XA(ks + 2, 0); pfB[ks & 1] = XA(ks + 2, 1); }
#pragma unroll
        for (int ct = 0; ct < 16; ++ct) {
            bf16x8 afr = *(const bf16x8*)(Ab + ((size_t)((ks * 4 + g16) * 256 + ct * 16 + col)) * 8);
            acc[ct][0] = __builtin_amdgcn_mfma_f32_16x16x32_bf16(afr, xa, acc[ct][0], 0, 0, 0);
            acc[ct][1] = __builtin_amdgcn_mfma_f32_16x16x32_bf16(afr, xv, acc[ct][1], 0, 0, 0);
        }
    }
#undef XA
#pragma unroll
    for (int ct = 0; ct < 16; ++ct)
#pragma unroll
        for (int nt = 0; nt < 2; ++nt) {
            int n = n_w + nt * 16 + col;
#pragma unroll
            for (int rr = 0; rr < 4; ++rr) {
                int c = ct * 16 + g16 * 4 + rr;
                ob[(size_t)c * N_ + n] = acc[ct][nt][rr] + beta_s[c];
            }
        }
}

// ------------- Pass 2 (fallback, small ws): gathers f32 x ----------------
__global__ __launch_bounds__(512) void k_out_f32(
        const float* __restrict__ x, const short* __restrict__ Abf,
        const float* __restrict__ beta, float* __restrict__ out) {
    __shared__ float beta_s[256];
    const int t = threadIdx.x, lane = t & 63, wave = t >> 6;
    const int nb = blockIdx.x, b = blockIdx.y;
    const int col = lane & 15, g16 = lane >> 4;
    const int n_w = nb * 256 + wave * 32;
    if (t < 256) beta_s[t] = beta[b * C_ + t];
    __syncthreads();
    const short* Ab = Abf + (size_t)b * C_ * C_;
    const float* xb = x + (size_t)b * CN_;
    float* ob = out + (size_t)b * CN_;

    f32x4 acc[16][2];
#pragma unroll
    for (int i = 0; i < 16; ++i) {
        acc[i][0] = f32x4{0.f, 0.f, 0.f, 0.f};
        acc[i][1] = f32x4{0.f, 0.f, 0.f, 0.f};
    }
    float pf[2][16];
#define XL(KS, NT, J) xb[(size_t)((KS)*32 + g16 * 8 + (J)) * N_ + n_w + (NT)*16 + col]
#pragma unroll
    for (int j = 0; j < 8; ++j) { pf[0][j] = XL(0, 0, j); pf[0][8 + j] = XL(0, 1, j); }
#pragma unroll
    for (int ks = 0; ks < 8; ++ks) {
        if (ks + 1 < 8) {
#pragma unroll
            for (int j = 0; j < 8; ++j) {
                pf[(ks + 1) & 1][j] = XL(ks + 1, 0, j);
                pf[(ks + 1) & 1][8 + j] = XL(ks + 1, 1, j);
            }
        }
        bf16x8 xa, xv;
#pragma unroll
        for (int j = 0; j < 8; ++j) {
            xa[j] = f2bf(pf[ks & 1][j]);
            xv[j] = f2bf(pf[ks & 1][8 + j]);
        }
#pragma unroll
        for (int ct = 0; ct < 16; ++ct) {
            bf16x8 afr = *(const bf16x8*)(Ab + ((size_t)((ks * 4 + g16) * 256 + ct * 16 + col)) * 8);
            acc[ct][0] = __builtin_amdgcn_mfma_f32_16x16x32_bf16(afr, xa, acc[ct][0], 0, 0, 0);
            acc[ct][1] = __builtin_amdgcn_mfma_f32_16x16x32_bf16(afr, xv, acc[ct][1], 0, 0, 0);
        }
    }
#undef XL
#pragma unroll
    for (int ct = 0; ct < 16; ++ct)
#pragma unroll
        for (int nt = 0; nt < 2; ++nt) {
            int n = n_w + nt * 16 + col;
#pragma unroll
            for (int rr = 0; rr < 4; ++rr) {
                int c = ct * 16 + g16 * 4 + rr;
                ob[(size_t)c * N_ + n] = acc[ct][nt][rr] + beta_s[c];
            }
        }
}

extern "C" void kernel_launch(void* const* d_in, const int* in_sizes, int n_in,
                              void* d_out, int out_size, void* d_ws, size_t ws_size,
                              hipStream_t stream) {
    (void)in_sizes; (void)n_in; (void)out_size;
    const float* x     = (const float*)d_in[0];
    const float* Wq    = (const float*)d_in[1];
    const float* bq    = (const float*)d_in[2];
    const float* Wk    = (const float*)d_in[3];
    const float* bk    = (const float*)d_in[4];
    const float* Wv    = (const float*)d_in[5];
    const float* bv    = (const float*)d_in[6];
    const float* outer = (const float*)d_in[7];
    float* out = (float*)d_out;

    char* w = (char*)d_ws;
    float* mean   = (float*)(w + 0);
    float* rsig   = (float*)(w + 2048);
    float* beta   = (float*)(w + 4096);
    float* rspart = (float*)(w + 8192);                 // 108*2*256*4 = 221184
    float* Graw   = (float*)(w + 262144);               // 512K
    float* P      = (float*)(w + 786432);               // 512K
    float* atten  = (float*)(w + 1310720);              // 512K
    short* Abf    = (short*)(w + 1835008);              // 256K
    const size_t fixed = 2097152;                       // 2 MB
    float* part = (float*)(w + fixed);                  // 56.6 MB
    short* xf   = (short*)(w + fixed);                  // 113.25 MB (aliases part)

    const size_t xf_bytes = (size_t)B_ * CN_ * 2;       // 113246208
    const bool big = ws_size >= fixed + xf_bytes;

    k_gram  <<<dim3(NCK_, B_), 1024, 0, stream>>>(x, part, rspart);
    k_reduce<<<dim3(B_ * C_), 256, 0, stream>>>(part, rspart, Graw, mean, rsig);
    k_gemm1 <<<dim3(B_ * C_), C_, 0, stream>>>(Wq, Graw, mean, rsig, P);
    k_attn  <<<dim3(B_ * C_), C_, 0, stream>>>(P, Wk, bq, bk, outer, atten);
    k_gemm3 <<<dim3(B_ * C_), C_, 0, stream>>>(atten, Wv, bv, mean, rsig, Abf, beta);
    if (big) {
        k_prepf <<<dim3(N_ / 128, 4, B_), 256, 0, stream>>>(x, xf);
        k_out_bf<<<dim3(N_ / 256, B_), 512, 0, stream>>>(xf, Abf, beta, out);
    } else {
        k_out_f32<<<dim3(N_ / 256, B_), 512, 0, stream>>>(x, Abf, beta, out);
    }
}

// Round 4
// 301.905 us; speedup vs baseline: 1.7485x; 1.1970x over previous
//
#include <hip/hip_runtime.h>
#include <hip/hip_bf16.h>

#define B_ 2
#define C_ 256
#define N_ 110592
#define CN_ ((size_t)C_ * N_)
#define NCK_ 108          // K-chunks in gram (divides 1728)
#define T_ 16             // 64-col tiles per chunk: 108*16*64 = 110592

typedef __attribute__((ext_vector_type(4))) float f32x4;
typedef __attribute__((ext_vector_type(8))) short bf16x8;
typedef __attribute__((ext_vector_type(4))) short bf16x4;

__device__ __forceinline__ short f2bf(float f) {
    union { float f; unsigned u; } v; v.f = f;
    unsigned r = (v.u + 0x7fffu + ((v.u >> 16) & 1u)) >> 16;
    return (short)(r & 0xffffu);
}

// ---------------- Pass 1: raw Gram (split-K) + rowsums -------------------
__global__ __launch_bounds__(1024) void k_gram(
        const float* __restrict__ x, float* __restrict__ part,
        float* __restrict__ rspart) {
    __shared__ short Xs[2 * 256 * 72];   // 2 buffers, 256 rows x 144B pitch
    __shared__ float rs_s[256];
    const int t = threadIdx.x, lane = t & 63, wave = t >> 6;
    const int chunk = blockIdx.x, b = blockIdx.y;
    const int k0 = chunk * (T_ * 64);
    const int f4 = t & 15;
    const int crow = t >> 4;
    const int cw0 = (wave & 3) * 64, dw0 = (wave >> 2) * 64;
    const int r16 = lane & 15, g16 = lane >> 4;
    const float* xb = x + (size_t)b * CN_;

    f32x4 acc[4][4];
#pragma unroll
    for (int i = 0; i < 4; ++i)
#pragma unroll
        for (int j = 0; j < 4; ++j) acc[i][j] = f32x4{0.f, 0.f, 0.f, 0.f};
    float rs[4] = {0.f, 0.f, 0.f, 0.f};

    f32x4 va[4];
#pragma unroll
    for (int q = 0; q < 4; ++q)
        va[q] = *(const f32x4*)(xb + (size_t)(q * 64 + crow) * N_ + k0 + f4 * 4);

    for (int tt = 0; tt < T_; ++tt) {
        const int buf = (tt & 1) * 18432;
#pragma unroll
        for (int q = 0; q < 4; ++q) {
            f32x4 v = va[q];
            rs[q] += (v.x + v.y) + (v.z + v.w);
            bf16x4 h;
            h.x = f2bf(v.x); h.y = f2bf(v.y); h.z = f2bf(v.z); h.w = f2bf(v.w);
            *(bf16x4*)(Xs + buf + (q * 64 + crow) * 72 + f4 * 4) = h;
        }
        __syncthreads();
        if (tt + 1 < T_) {
#pragma unroll
            for (int q = 0; q < 4; ++q)
                va[q] = *(const f32x4*)(xb + (size_t)(q * 64 + crow) * N_ +
                                        k0 + (tt + 1) * 64 + f4 * 4);
        }
#pragma unroll
        for (int k2 = 0; k2 < 2; ++k2) {
            bf16x8 afr[4];
#pragma unroll
            for (int ct = 0; ct < 4; ++ct)
                afr[ct] = *(const bf16x8*)(Xs + buf + (cw0 + ct * 16 + r16) * 72 +
                                           (k2 * 4 + g16) * 8);
#pragma unroll
            for (int dt = 0; dt < 4; ++dt) {
                bf16x8 bfr = *(const bf16x8*)(Xs + buf + (dw0 + dt * 16 + r16) * 72 +
                                              (k2 * 4 + g16) * 8);
#pragma unroll
                for (int ct = 0; ct < 4; ++ct)
                    acc[ct][dt] = __builtin_amdgcn_mfma_f32_16x16x32_bf16(
                        afr[ct], bfr, acc[ct][dt], 0, 0, 0);
            }
        }
    }

#pragma unroll
    for (int q = 0; q < 4; ++q) {
        float r = rs[q];
        r += __shfl_xor(r, 1);
        r += __shfl_xor(r, 2);
        r += __shfl_xor(r, 4);
        r += __shfl_xor(r, 8);
        if ((t & 15) == 0) rs_s[q * 64 + crow] = r;
    }
    __syncthreads();
    if (t < 256) rspart[((size_t)b * NCK_ + chunk) * C_ + t] = rs_s[t];

    float* pp = part + ((size_t)b * NCK_ + chunk) * (C_ * C_);
#pragma unroll
    for (int ct = 0; ct < 4; ++ct)
#pragma unroll
        for (int dt = 0; dt < 4; ++dt) {
            int d = dw0 + dt * 16 + r16;
#pragma unroll
            for (int rr = 0; rr < 4; ++rr) {
                int c = cw0 + ct * 16 + g16 * 4 + rr;
                pp[(size_t)c * C_ + d] = acc[ct][dt][rr];
            }
        }
}

// ------------- reduce partial Grams + fused stats (mean, rsig) -----------
__global__ void k_reduce(const float* __restrict__ part, const float* __restrict__ rspart,
                         float* __restrict__ Graw, float* __restrict__ mean,
                         float* __restrict__ rsig) {
    __shared__ float diag_s;
    __shared__ float red[256];
    int bid = blockIdx.x;
    int b = bid >> 8, c = bid & 255;
    int d = threadIdx.x;
    float s = 0.f;
    for (int p = 0; p < NCK_; ++p)
        s += part[(((size_t)b * NCK_ + p) * (C_ * C_)) + (size_t)c * C_ + d];
    Graw[((size_t)b * C_ + c) * C_ + d] = s;
    if (d == c) diag_s = s;
    float rsum = 0.f;
    for (int p = d; p < NCK_; p += 256)
        rsum += rspart[((size_t)b * NCK_ + p) * C_ + c];
    red[d] = rsum;
    __syncthreads();
    if (d < 128) red[d] += red[d + 128];
    __syncthreads();
    if (d < 64) red[d] += red[d + 64];
    __syncthreads();
    if (d == 0) {
        float tot = 0.f;
#pragma unroll
        for (int i = 0; i < 64; ++i) tot += red[i];
        float m = tot / (float)N_;
        float var = diag_s / (float)N_ - m * m;
        mean[b * C_ + c] = m;
        rsig[b * C_ + c] = rsqrtf(var + 1e-5f);
    }
}

// ---------------- P = Wq * Gn ----------------
__global__ void k_gemm1(const float* __restrict__ Wq, const float* __restrict__ Graw,
                        const float* __restrict__ mean, const float* __restrict__ rsig,
                        float* __restrict__ P) {
    int bid = blockIdx.x; int b = bid >> 8, c = bid & 255; int d = threadIdx.x;
    const float* G = Graw + (size_t)b * C_ * C_;
    const float* mb = mean + b * C_;
    const float* rb = rsig + b * C_;
    float md = mb[d], rd = rb[d];
    float a1 = 0.f, a2 = 0.f;
    for (int e = 0; e < C_; ++e) {
        float w = Wq[(size_t)c * C_ + e] * rb[e];
        a1 += w * G[(size_t)e * C_ + d];
        a2 += w * mb[e];
    }
    P[((size_t)b * C_ + c) * C_ + d] = rd * a1 - (float)N_ * md * rd * a2;
}

// ---------------- atten = softmax(P*Wk^T + N bq bk^T)/16 + outer/16 ------
__global__ void k_attn(const float* __restrict__ P, const float* __restrict__ Wk,
                       const float* __restrict__ bq, const float* __restrict__ bk,
                       const float* __restrict__ outer, float* __restrict__ atten) {
    __shared__ float Pr_s[256];
    __shared__ float red[8];
    int bid = blockIdx.x; int b = bid >> 8, c = bid & 255; int d = threadIdx.x;
    int lane = d & 63, w = d >> 6;
    Pr_s[d] = P[((size_t)b * C_ + c) * C_ + d];
    __syncthreads();
    float a = 0.f;
#pragma unroll 4
    for (int e4 = 0; e4 < 64; ++e4) {
        f32x4 wv = *(const f32x4*)(Wk + (size_t)d * C_ + e4 * 4);
        f32x4 pv = *(const f32x4*)(Pr_s + e4 * 4);
        a += wv.x * pv.x + wv.y * pv.y + wv.z * pv.z + wv.w * pv.w;
    }
    float v = a + (float)N_ * bq[c] * bk[d];
    float m = v;
    for (int off = 32; off; off >>= 1) m = fmaxf(m, __shfl_xor(m, off));
    if (lane == 0) red[w] = m;
    __syncthreads();
    m = fmaxf(fmaxf(red[0], red[1]), fmaxf(red[2], red[3]));
    float e = __expf(v - m);
    float s = e;
    for (int off = 32; off; off >>= 1) s += __shfl_xor(s, off);
    if (lane == 0) red[4 + w] = s;
    __syncthreads();
    s = red[4] + red[5] + red[6] + red[7];
    atten[((size_t)b * C_ + c) * C_ + d] = e / (s * 16.f) + outer[(size_t)c * C_ + d] * 0.0625f;
}

// ------------- A = (atten*Wv + I)*diag(rsig) in FRAGMENT layout, beta ----
__global__ void k_gemm3(const float* __restrict__ atten, const float* __restrict__ Wv,
                        const float* __restrict__ bv, const float* __restrict__ mean,
                        const float* __restrict__ rsig, short* __restrict__ Abf,
                        float* __restrict__ beta) {
    __shared__ float red[4];
    int bid = blockIdx.x; int b = bid >> 8, c = bid & 255; int g = threadIdx.x;
    int lane = g & 63, w = g >> 6;
    const float* at = atten + ((size_t)b * C_ + c) * C_;
    float a = 0.f;
    for (int d = 0; d < C_; ++d)
        a += at[d] * Wv[(size_t)d * C_ + g];
    float Ag = (a + ((g == c) ? 1.f : 0.f)) * rsig[b * C_ + g];
    Abf[(size_t)b * C_ * C_ + ((size_t)(g >> 3) * C_ + c) * 8 + (g & 7)] = f2bf(Ag);
    float u = at[g] * bv[g] - Ag * mean[b * C_ + g];
    for (int off = 32; off; off >>= 1) u += __shfl_xor(u, off);
    if (lane == 0) red[w] = u;
    __syncthreads();
    if (g == 0) beta[b * C_ + c] = red[0] + red[1] + red[2] + red[3];
}

// ------------- prep: f32 x -> ch-packed bf16 xf[b][kgrp][n][8] -----------
__global__ __launch_bounds__(256) void k_prepf(
        const float* __restrict__ x, short* __restrict__ xf) {
    __shared__ float Xf[64 * 132];
    const int t = threadIdx.x;
    const int n0 = blockIdx.x * 128, ctile = blockIdx.y, b = blockIdx.z;
    const int c0 = ctile * 64;
    const float* xb = x + (size_t)b * CN_;
    short* xfb = xf + (size_t)b * CN_;
#pragma unroll
    for (int i = 0; i < 8; ++i) {
        int row = i * 8 + (t >> 5), f4 = t & 31;
        f32x4 v = *(const f32x4*)(xb + (size_t)(c0 + row) * N_ + n0 + f4 * 4);
        *(f32x4*)(Xf + row * 132 + f4 * 4) = v;
    }
    __syncthreads();
#pragma unroll
    for (int it = 0; it < 4; ++it) {
        int cg = it * 2 + (t >> 7), n = t & 127;
        bf16x8 h;
#pragma unroll
        for (int j = 0; j < 8; ++j)
            h[j] = f2bf(Xf[(cg * 8 + j) * 132 + n]);
        *(bf16x8*)(xfb + ((size_t)(ctile * 8 + cg) * N_ + n0 + n) * 8) = h;
    }
}

// ------------- Pass 2 (main): out = A*x + beta -----------------------------
// 512 thr = 4 c-quads x 2 n-halves. A-slice (64 rows) preloaded in regs
// (128 VGPR), reused over 8 n-tiles of 64. Stores via wave-private LDS
// transpose -> dwordx4 full-line segments. No barriers in main loop.
#define PITCH 37
__global__ __launch_bounds__(512, 2) void k_out_bf(
        const short* __restrict__ xf, const short* __restrict__ Abf,
        const float* __restrict__ beta, float* __restrict__ out) {
    __shared__ float Wlds[8 * 64 * PITCH];
    __shared__ float beta_s[256];
    const int t = threadIdx.x, lane = t & 63, wave = t >> 6;
    const int nb = blockIdx.x, b = blockIdx.y;
    const int col = lane & 15, g16 = lane >> 4;
    const int cq = wave & 3, nh = wave >> 2;
    const int cw0 = cq * 64;
    if (t < 256) beta_s[t] = beta[b * C_ + t];
    __syncthreads();
    const short* Ab = Abf + (size_t)b * C_ * C_;
    const short* xfb = xf + (size_t)b * CN_;
    float* ob = out + (size_t)b * CN_;
    float* wl = Wlds + wave * (64 * PITCH);

    // preload A-slice: rows cw0..cw0+63, all 256 ch -> 32 frags (128 VGPR)
    bf16x8 Af[4][8];
#pragma unroll
    for (int ct = 0; ct < 4; ++ct)
#pragma unroll
        for (int ks = 0; ks < 8; ++ks)
            Af[ct][ks] = *(const bf16x8*)(Ab +
                ((size_t)((ks * 4 + g16) * 256 + cw0 + ct * 16 + col)) * 8);

    const int r8 = lane >> 3, s8 = lane & 7;

    for (int it = 0; it < 8; ++it) {
        const int n0w = nb * 512 + it * 64 + nh * 32;
        bf16x8 xr0[8], xr1[8];
#pragma unroll
        for (int ks = 0; ks < 8; ++ks)
            xr0[ks] = *(const bf16x8*)(xfb + ((size_t)(ks * 4 + g16) * N_ + n0w + col) * 8);
#pragma unroll
        for (int ks = 0; ks < 8; ++ks)
            xr1[ks] = *(const bf16x8*)(xfb + ((size_t)(ks * 4 + g16) * N_ + n0w + 16 + col) * 8);

        f32x4 acc[4][2];
#pragma unroll
        for (int i = 0; i < 4; ++i) {
            acc[i][0] = f32x4{0.f, 0.f, 0.f, 0.f};
            acc[i][1] = f32x4{0.f, 0.f, 0.f, 0.f};
        }
#pragma unroll
        for (int ks = 0; ks < 8; ++ks)
#pragma unroll
            for (int ct = 0; ct < 4; ++ct) {
                acc[ct][0] = __builtin_amdgcn_mfma_f32_16x16x32_bf16(Af[ct][ks], xr0[ks], acc[ct][0], 0, 0, 0);
                acc[ct][1] = __builtin_amdgcn_mfma_f32_16x16x32_bf16(Af[ct][ks], xr1[ks], acc[ct][1], 0, 0, 0);
            }
        // transpose through wave-private LDS
#pragma unroll
        for (int ct = 0; ct < 4; ++ct)
#pragma unroll
            for (int nt = 0; nt < 2; ++nt)
#pragma unroll
                for (int rr = 0; rr < 4; ++rr)
                    wl[(ct * 16 + g16 * 4 + rr) * PITCH + nt * 16 + col] = acc[ct][nt][rr];
#pragma unroll
        for (int i = 0; i < 8; ++i) {
            int row = i * 8 + r8;
            f32x4 v = *(const f32x4*)(wl + row * PITCH + s8 * 4);
            float bb = beta_s[cw0 + row];
            v.x += bb; v.y += bb; v.z += bb; v.w += bb;
            *(f32x4*)(ob + (size_t)(cw0 + row) * N_ + n0w + s8 * 4) = v;
        }
    }
}

// ------------- Pass 2 (fallback, small ws): gathers f32 x ----------------
__global__ __launch_bounds__(512) void k_out_f32(
        const float* __restrict__ x, const short* __restrict__ Abf,
        const float* __restrict__ beta, float* __restrict__ out) {
    __shared__ float beta_s[256];
    const int t = threadIdx.x, lane = t & 63, wave = t >> 6;
    const int nb = blockIdx.x, b = blockIdx.y;
    const int col = lane & 15, g16 = lane >> 4;
    const int n_w = nb * 256 + wave * 32;
    if (t < 256) beta_s[t] = beta[b * C_ + t];
    __syncthreads();
    const short* Ab = Abf + (size_t)b * C_ * C_;
    const float* xb = x + (size_t)b * CN_;
    float* ob = out + (size_t)b * CN_;

    f32x4 acc[16][2];
#pragma unroll
    for (int i = 0; i < 16; ++i) {
        acc[i][0] = f32x4{0.f, 0.f, 0.f, 0.f};
        acc[i][1] = f32x4{0.f, 0.f, 0.f, 0.f};
    }
    float pf[2][16];
#define XL(KS, NT, J) xb[(size_t)((KS)*32 + g16 * 8 + (J)) * N_ + n_w + (NT)*16 + col]
#pragma unroll
    for (int j = 0; j < 8; ++j) { pf[0][j] = XL(0, 0, j); pf[0][8 + j] = XL(0, 1, j); }
#pragma unroll
    for (int ks = 0; ks < 8; ++ks) {
        if (ks + 1 < 8) {
#pragma unroll
            for (int j = 0; j < 8; ++j) {
                pf[(ks + 1) & 1][j] = XL(ks + 1, 0, j);
                pf[(ks + 1) & 1][8 + j] = XL(ks + 1, 1, j);
            }
        }
        bf16x8 xa, xv;
#pragma unroll
        for (int j = 0; j < 8; ++j) {
            xa[j] = f2bf(pf[ks & 1][j]);
            xv[j] = f2bf(pf[ks & 1][8 + j]);
        }
#pragma unroll
        for (int ct = 0; ct < 16; ++ct) {
            bf16x8 afr = *(const bf16x8*)(Ab + ((size_t)((ks * 4 + g16) * 256 + ct * 16 + col)) * 8);
            acc[ct][0] = __builtin_amdgcn_mfma_f32_16x16x32_bf16(afr, xa, acc[ct][0], 0, 0, 0);
            acc[ct][1] = __builtin_amdgcn_mfma_f32_16x16x32_bf16(afr, xv, acc[ct][1], 0, 0, 0);
        }
    }
#undef XL
#pragma unroll
    for (int ct = 0; ct < 16; ++ct)
#pragma unroll
        for (int nt = 0; nt < 2; ++nt) {
            int n = n_w + nt * 16 + col;
#pragma unroll
            for (int rr = 0; rr < 4; ++rr) {
                int c = ct * 16 + g16 * 4 + rr;
                ob[(size_t)c * N_ + n] = acc[ct][nt][rr] + beta_s[c];
            }
        }
}

extern "C" void kernel_launch(void* const* d_in, const int* in_sizes, int n_in,
                              void* d_out, int out_size, void* d_ws, size_t ws_size,
                              hipStream_t stream) {
    (void)in_sizes; (void)n_in; (void)out_size;
    const float* x     = (const float*)d_in[0];
    const float* Wq    = (const float*)d_in[1];
    const float* bq    = (const float*)d_in[2];
    const float* Wk    = (const float*)d_in[3];
    const float* bk    = (const float*)d_in[4];
    const float* Wv    = (const float*)d_in[5];
    const float* bv    = (const float*)d_in[6];
    const float* outer = (const float*)d_in[7];
    float* out = (float*)d_out;

    char* w = (char*)d_ws;
    float* mean   = (float*)(w + 0);
    float* rsig   = (float*)(w + 2048);
    float* beta   = (float*)(w + 4096);
    float* rspart = (float*)(w + 8192);                 // 108*2*256*4 = 221184
    float* Graw   = (float*)(w + 262144);               // 512K
    float* P      = (float*)(w + 786432);               // 512K
    float* atten  = (float*)(w + 1310720);              // 512K
    short* Abf    = (short*)(w + 1835008);              // 256K
    const size_t fixed = 2097152;                       // 2 MB
    float* part = (float*)(w + fixed);                  // 56.6 MB
    short* xf   = (short*)(w + fixed);                  // 113.25 MB (aliases part)

    const size_t xf_bytes = (size_t)B_ * CN_ * 2;       // 113246208
    const bool big = ws_size >= fixed + xf_bytes;

    k_gram  <<<dim3(NCK_, B_), 1024, 0, stream>>>(x, part, rspart);
    k_reduce<<<dim3(B_ * C_), 256, 0, stream>>>(part, rspart, Graw, mean, rsig);
    k_gemm1 <<<dim3(B_ * C_), C_, 0, stream>>>(Wq, Graw, mean, rsig, P);
    k_attn  <<<dim3(B_ * C_), C_, 0, stream>>>(P, Wk, bq, bk, outer, atten);
    k_gemm3 <<<dim3(B_ * C_), C_, 0, stream>>>(atten, Wv, bv, mean, rsig, Abf, beta);
    if (big) {
        k_prepf <<<dim3(N_ / 128, 4, B_), 256, 0, stream>>>(x, xf);
        k_out_bf<<<dim3(N_ / 512, B_), 512, 0, stream>>>(xf, Abf, beta, out);
    } else {
        k_out_f32<<<dim3(N_ / 256, B_), 512, 0, stream>>>(x, Abf, beta, out);
    }
}

// Round 5
// 230.665 us; speedup vs baseline: 2.2885x; 1.3088x over previous
//
#include <hip/hip_runtime.h>
#include <hip/hip_bf16.h>

#define B_ 2
#define C_ 256
#define N_ 110592
#define CN_ ((size_t)C_ * N_)
#define NCK_ 108          // K-chunks in gram (divides 1728)
#define T_ 16             // 64-col tiles per chunk: 108*16*64 = 110592

typedef __attribute__((ext_vector_type(4))) float f32x4;
typedef __attribute__((ext_vector_type(8))) short bf16x8;
typedef __attribute__((ext_vector_type(4))) short bf16x4;

__device__ __forceinline__ short f2bf(float f) {
    union { float f; unsigned u; } v; v.f = f;
    unsigned r = (v.u + 0x7fffu + ((v.u >> 16) & 1u)) >> 16;
    return (short)(r & 0xffffu);
}

__device__ __forceinline__ void gload16(const short* g, short* l) {
    __builtin_amdgcn_global_load_lds(
        (const __attribute__((address_space(1))) void*)g,
        (__attribute__((address_space(3))) void*)l, 16, 0, 0);
}

// ---------------- Pass 1: raw Gram (split-K) + rowsums + xf emit ----------
// 1024 thr / 16 waves, wave-tile 64x64. 2-phase reg-staged pipeline.
// Also converts x -> bf16 fragment-layout xf (reuses the LDS tile), saving
// a separate prep pass over x.
__global__ __launch_bounds__(1024, 4) void k_gram(
        const float* __restrict__ x, float* __restrict__ part,
        float* __restrict__ rspart, short* __restrict__ xf, int wxf) {
    __shared__ short Xs[2 * 256 * 72];   // 2 buffers, 256 rows x 144B pitch
    __shared__ float rs_s[256];
    const int t = threadIdx.x, lane = t & 63, wave = t >> 6;
    const int chunk = blockIdx.x, b = blockIdx.y;
    const int k0 = chunk * (T_ * 64);
    const int f4 = t & 15;
    const int crow = t >> 4;
    const int cw0 = (wave & 3) * 64, dw0 = (wave >> 2) * 64;
    const int r16 = lane & 15, g16 = lane >> 4;
    const float* xb = x + (size_t)b * CN_;
    short* xfb = xf + (size_t)b * CN_;

    f32x4 acc[4][4];
#pragma unroll
    for (int i = 0; i < 4; ++i)
#pragma unroll
        for (int j = 0; j < 4; ++j) acc[i][j] = f32x4{0.f, 0.f, 0.f, 0.f};
    float rs[4] = {0.f, 0.f, 0.f, 0.f};

    f32x4 va[4];
#pragma unroll
    for (int q = 0; q < 4; ++q)
        va[q] = *(const f32x4*)(xb + (size_t)(q * 64 + crow) * N_ + k0 + f4 * 4);

    for (int tt = 0; tt < T_; ++tt) {
        const int buf = (tt & 1) * 18432;
#pragma unroll
        for (int q = 0; q < 4; ++q) {
            f32x4 v = va[q];
            rs[q] += (v.x + v.y) + (v.z + v.w);
            bf16x4 h;
            h.x = f2bf(v.x); h.y = f2bf(v.y); h.z = f2bf(v.z); h.w = f2bf(v.w);
            *(bf16x4*)(Xs + buf + (q * 64 + crow) * 72 + f4 * 4) = h;
        }
        __syncthreads();
        if (tt + 1 < T_) {
#pragma unroll
            for (int q = 0; q < 4; ++q)
                va[q] = *(const f32x4*)(xb + (size_t)(q * 64 + crow) * N_ +
                                        k0 + (tt + 1) * 64 + f4 * 4);
        }
        // emit xf (bf16 fragment layout) from the staged LDS tile
        if (wxf) {
            const int kglob0 = k0 + tt * 64;
#pragma unroll
            for (int i2 = 0; i2 < 2; ++i2) {
                int s = i2 * 1024 + t;
                int kg = s >> 6, nn = s & 63;
                bf16x8 h;
#pragma unroll
                for (int j = 0; j < 8; ++j)
                    h[j] = Xs[buf + (kg * 8 + j) * 72 + nn];
                *(bf16x8*)(xfb + ((size_t)kg * N_ + kglob0 + nn) * 8) = h;
            }
        }
#pragma unroll
        for (int k2 = 0; k2 < 2; ++k2) {
            bf16x8 afr[4];
#pragma unroll
            for (int ct = 0; ct < 4; ++ct)
                afr[ct] = *(const bf16x8*)(Xs + buf + (cw0 + ct * 16 + r16) * 72 +
                                           (k2 * 4 + g16) * 8);
#pragma unroll
            for (int dt = 0; dt < 4; ++dt) {
                bf16x8 bfr = *(const bf16x8*)(Xs + buf + (dw0 + dt * 16 + r16) * 72 +
                                              (k2 * 4 + g16) * 8);
#pragma unroll
                for (int ct = 0; ct < 4; ++ct)
                    acc[ct][dt] = __builtin_amdgcn_mfma_f32_16x16x32_bf16(
                        afr[ct], bfr, acc[ct][dt], 0, 0, 0);
            }
        }
    }

#pragma unroll
    for (int q = 0; q < 4; ++q) {
        float r = rs[q];
        r += __shfl_xor(r, 1);
        r += __shfl_xor(r, 2);
        r += __shfl_xor(r, 4);
        r += __shfl_xor(r, 8);
        if ((t & 15) == 0) rs_s[q * 64 + crow] = r;
    }
    __syncthreads();
    if (t < 256) rspart[((size_t)b * NCK_ + chunk) * C_ + t] = rs_s[t];

    float* pp = part + ((size_t)b * NCK_ + chunk) * (C_ * C_);
#pragma unroll
    for (int ct = 0; ct < 4; ++ct)
#pragma unroll
        for (int dt = 0; dt < 4; ++dt) {
            int d = dw0 + dt * 16 + r16;
#pragma unroll
            for (int rr = 0; rr < 4; ++rr) {
                int c = cw0 + ct * 16 + g16 * 4 + rr;
                pp[(size_t)c * C_ + d] = acc[ct][dt][rr];
            }
        }
}

// ------------- reduce partial Grams + fused stats (mean, rsig) -----------
__global__ void k_reduce(const float* __restrict__ part, const float* __restrict__ rspart,
                         float* __restrict__ Graw, float* __restrict__ mean,
                         float* __restrict__ rsig) {
    __shared__ float diag_s;
    __shared__ float red[256];
    int bid = blockIdx.x;
    int b = bid >> 8, c = bid & 255;
    int d = threadIdx.x;
    float s = 0.f;
    for (int p = 0; p < NCK_; ++p)
        s += part[(((size_t)b * NCK_ + p) * (C_ * C_)) + (size_t)c * C_ + d];
    Graw[((size_t)b * C_ + c) * C_ + d] = s;
    if (d == c) diag_s = s;
    float rsum = 0.f;
    for (int p = d; p < NCK_; p += 256)
        rsum += rspart[((size_t)b * NCK_ + p) * C_ + c];
    red[d] = rsum;
    __syncthreads();
    if (d < 128) red[d] += red[d + 128];
    __syncthreads();
    if (d < 64) red[d] += red[d + 64];
    __syncthreads();
    if (d == 0) {
        float tot = 0.f;
#pragma unroll
        for (int i = 0; i < 64; ++i) tot += red[i];
        float m = tot / (float)N_;
        float var = diag_s / (float)N_ - m * m;
        mean[b * C_ + c] = m;
        rsig[b * C_ + c] = rsqrtf(var + 1e-5f);
    }
}

// ---------------- P = Wq * Gn ----------------
__global__ void k_gemm1(const float* __restrict__ Wq, const float* __restrict__ Graw,
                        const float* __restrict__ mean, const float* __restrict__ rsig,
                        float* __restrict__ P) {
    int bid = blockIdx.x; int b = bid >> 8, c = bid & 255; int d = threadIdx.x;
    const float* G = Graw + (size_t)b * C_ * C_;
    const float* mb = mean + b * C_;
    const float* rb = rsig + b * C_;
    float md = mb[d], rd = rb[d];
    float a1 = 0.f, a2 = 0.f;
    for (int e = 0; e < C_; ++e) {
        float w = Wq[(size_t)c * C_ + e] * rb[e];
        a1 += w * G[(size_t)e * C_ + d];
        a2 += w * mb[e];
    }
    P[((size_t)b * C_ + c) * C_ + d] = rd * a1 - (float)N_ * md * rd * a2;
}

// ---------------- atten = softmax(P*Wk^T + N bq bk^T)/16 + outer/16 ------
__global__ void k_attn(const float* __restrict__ P, const float* __restrict__ Wk,
                       const float* __restrict__ bq, const float* __restrict__ bk,
                       const float* __restrict__ outer, float* __restrict__ atten) {
    __shared__ float Pr_s[256];
    __shared__ float red[8];
    int bid = blockIdx.x; int b = bid >> 8, c = bid & 255; int d = threadIdx.x;
    int lane = d & 63, w = d >> 6;
    Pr_s[d] = P[((size_t)b * C_ + c) * C_ + d];
    __syncthreads();
    float a = 0.f;
#pragma unroll 4
    for (int e4 = 0; e4 < 64; ++e4) {
        f32x4 wv = *(const f32x4*)(Wk + (size_t)d * C_ + e4 * 4);
        f32x4 pv = *(const f32x4*)(Pr_s + e4 * 4);
        a += wv.x * pv.x + wv.y * pv.y + wv.z * pv.z + wv.w * pv.w;
    }
    float v = a + (float)N_ * bq[c] * bk[d];
    float m = v;
    for (int off = 32; off; off >>= 1) m = fmaxf(m, __shfl_xor(m, off));
    if (lane == 0) red[w] = m;
    __syncthreads();
    m = fmaxf(fmaxf(red[0], red[1]), fmaxf(red[2], red[3]));
    float e = __expf(v - m);
    float s = e;
    for (int off = 32; off; off >>= 1) s += __shfl_xor(s, off);
    if (lane == 0) red[4 + w] = s;
    __syncthreads();
    s = red[4] + red[5] + red[6] + red[7];
    atten[((size_t)b * C_ + c) * C_ + d] = e / (s * 16.f) + outer[(size_t)c * C_ + d] * 0.0625f;
}

// ------------- A = (atten*Wv + I)*diag(rsig) in FRAGMENT layout, beta ----
__global__ void k_gemm3(const float* __restrict__ atten, const float* __restrict__ Wv,
                        const float* __restrict__ bv, const float* __restrict__ mean,
                        const float* __restrict__ rsig, short* __restrict__ Abf,
                        float* __restrict__ beta) {
    __shared__ float red[4];
    int bid = blockIdx.x; int b = bid >> 8, c = bid & 255; int g = threadIdx.x;
    int lane = g & 63, w = g >> 6;
    const float* at = atten + ((size_t)b * C_ + c) * C_;
    float a = 0.f;
    for (int d = 0; d < C_; ++d)
        a += at[d] * Wv[(size_t)d * C_ + g];
    float Ag = (a + ((g == c) ? 1.f : 0.f)) * rsig[b * C_ + g];
    Abf[(size_t)b * C_ * C_ + ((size_t)(g >> 3) * C_ + c) * 8 + (g & 7)] = f2bf(Ag);
    float u = at[g] * bv[g] - Ag * mean[b * C_ + g];
    for (int off = 32; off; off >>= 1) u += __shfl_xor(u, off);
    if (lane == 0) red[w] = u;
    __syncthreads();
    if (g == 0) beta[b * C_ + c] = red[0] + red[1] + red[2] + red[3];
}

// ------------- Pass 2: out = A*x + beta ------------------------------------
// 512 thr / 8 waves; wave w owns c-rows [32w, 32w+32) with A-slice in regs
// (64 VGPR). x-tile (32 kgrp x 32 n, 16 KB) shared by all waves via
// global_load_lds double-buffer; slot index XOR-swizzled (nn^(kgrp&3)) on
// the GLOBAL source so frag ds_reads are <=2-way. Stores via wave-private
// padded LDS transpose -> 128B-segment dwordx4.
__global__ __launch_bounds__(512, 4) void k_out2(
        const short* __restrict__ xf, const short* __restrict__ Abf,
        const float* __restrict__ beta, float* __restrict__ out) {
    __shared__ short Xt[2 * 8192];      // 2 x 16 KB
    __shared__ float Wb[8 * 32 * 33];   // wave-private store-transpose
    const int t = threadIdx.x, lane = t & 63, wave = t >> 6;
    const int nb = blockIdx.x, b = blockIdx.y;
    const int col = lane & 15, g16 = lane >> 4;
    const int cw0 = wave * 32;
    const int r8 = lane >> 3, s8 = lane & 7;
    const int n_blk = nb * 256;
    const short* Ab = Abf + (size_t)b * C_ * C_;
    const short* xfb = xf + (size_t)b * CN_;
    float* ob = out + (size_t)b * CN_;
    float* wl = Wb + wave * (32 * 33);

    // A-slice preload: 16 frags = 64 VGPR
    bf16x8 Af[2][8];
#pragma unroll
    for (int ct = 0; ct < 2; ++ct)
#pragma unroll
        for (int ks = 0; ks < 8; ++ks)
            Af[ct][ks] = *(const bf16x8*)(Ab +
                ((size_t)((ks * 4 + g16) * 256 + cw0 + ct * 16 + col)) * 8);
    float bet[4];
#pragma unroll
    for (int j = 0; j < 4; ++j) bet[j] = beta[b * C_ + cw0 + j * 8 + r8];

#define STAGE(BUF, N0)                                                        \
    {                                                                         \
        _Pragma("unroll")                                                     \
        for (int r = 0; r < 2; ++r) {                                         \
            int s = r * 512 + t;                                              \
            int kg = s >> 5, nsl = s & 31;                                    \
            int nn = nsl ^ (kg & 3);                                          \
            gload16(xfb + ((size_t)kg * N_ + (N0) + nn) * 8,                  \
                    Xt + (BUF) * 8192 + s * 8);                               \
        }                                                                     \
    }

    STAGE(0, n_blk)
    __syncthreads();

    for (int it = 0; it < 8; ++it) {
        const int cur = it & 1;
        if (it + 1 < 8) STAGE(cur ^ 1, n_blk + (it + 1) * 32)
        const int n0 = n_blk + it * 32;

        f32x4 acc[2][2];
#pragma unroll
        for (int i = 0; i < 2; ++i) {
            acc[i][0] = f32x4{0.f, 0.f, 0.f, 0.f};
            acc[i][1] = f32x4{0.f, 0.f, 0.f, 0.f};
        }
#pragma unroll
        for (int ks = 0; ks < 8; ++ks) {
            const int kg = ks * 4 + g16;
            bf16x8 x0 = *(const bf16x8*)(Xt + cur * 8192 +
                                         (kg * 32 + (col ^ (kg & 3))) * 8);
            bf16x8 x1 = *(const bf16x8*)(Xt + cur * 8192 +
                                         (kg * 32 + ((16 + col) ^ (kg & 3))) * 8);
            acc[0][0] = __builtin_amdgcn_mfma_f32_16x16x32_bf16(Af[0][ks], x0, acc[0][0], 0, 0, 0);
            acc[1][0] = __builtin_amdgcn_mfma_f32_16x16x32_bf16(Af[1][ks], x0, acc[1][0], 0, 0, 0);
            acc[0][1] = __builtin_amdgcn_mfma_f32_16x16x32_bf16(Af[0][ks], x1, acc[0][1], 0, 0, 0);
            acc[1][1] = __builtin_amdgcn_mfma_f32_16x16x32_bf16(Af[1][ks], x1, acc[1][1], 0, 0, 0);
        }
        // wave-private transpose (pitch 33 -> ~2-way banks)
#pragma unroll
        for (int ct = 0; ct < 2; ++ct)
#pragma unroll
            for (int nt = 0; nt < 2; ++nt)
#pragma unroll
                for (int rr = 0; rr < 4; ++rr)
                    wl[(ct * 16 + g16 * 4 + rr) * 33 + nt * 16 + col] = acc[ct][nt][rr];
#pragma unroll
        for (int j = 0; j < 4; ++j) {
            f32x4 v = *(const f32x4*)(wl + (j * 8 + r8) * 33 + s8 * 4);
            float bb = bet[j];
            v.x += bb; v.y += bb; v.z += bb; v.w += bb;
            *(f32x4*)(ob + (size_t)(cw0 + j * 8 + r8) * N_ + n0 + s8 * 4) = v;
        }
        __syncthreads();
    }
#undef STAGE
}

// ------------- Pass 2 (fallback, small ws): gathers f32 x ----------------
__global__ __launch_bounds__(512) void k_out_f32(
        const float* __restrict__ x, const short* __restrict__ Abf,
        const float* __restrict__ beta, float* __restrict__ out) {
    __shared__ float beta_s[256];
    const int t = threadIdx.x, lane = t & 63, wave = t >> 6;
    const int nb = blockIdx.x, b = blockIdx.y;
    const int col = lane & 15, g16 = lane >> 4;
    const int n_w = nb * 256 + wave * 32;
    if (t < 256) beta_s[t] = beta[b * C_ + t];
    __syncthreads();
    const short* Ab = Abf + (size_t)b * C_ * C_;
    const float* xb = x + (size_t)b * CN_;
    float* ob = out + (size_t)b * CN_;

    f32x4 acc[16][2];
#pragma unroll
    for (int i = 0; i < 16; ++i) {
        acc[i][0] = f32x4{0.f, 0.f, 0.f, 0.f};
        acc[i][1] = f32x4{0.f, 0.f, 0.f, 0.f};
    }
    float pf[2][16];
#define XL(KS, NT, J) xb[(size_t)((KS)*32 + g16 * 8 + (J)) * N_ + n_w + (NT)*16 + col]
#pragma unroll
    for (int j = 0; j < 8; ++j) { pf[0][j] = XL(0, 0, j); pf[0][8 + j] = XL(0, 1, j); }
#pragma unroll
    for (int ks = 0; ks < 8; ++ks) {
        if (ks + 1 < 8) {
#pragma unroll
            for (int j = 0; j < 8; ++j) {
                pf[(ks + 1) & 1][j] = XL(ks + 1, 0, j);
                pf[(ks + 1) & 1][8 + j] = XL(ks + 1, 1, j);
            }
        }
        bf16x8 xa, xv;
#pragma unroll
        for (int j = 0; j < 8; ++j) {
            xa[j] = f2bf(pf[ks & 1][j]);
            xv[j] = f2bf(pf[ks & 1][8 + j]);
        }
#pragma unroll
        for (int ct = 0; ct < 16; ++ct) {
            bf16x8 afr = *(const bf16x8*)(Ab + ((size_t)((ks * 4 + g16) * 256 + ct * 16 + col)) * 8);
            acc[ct][0] = __builtin_amdgcn_mfma_f32_16x16x32_bf16(afr, xa, acc[ct][0], 0, 0, 0);
            acc[ct][1] = __builtin_amdgcn_mfma_f32_16x16x32_bf16(afr, xv, acc[ct][1], 0, 0, 0);
        }
    }
#undef XL
#pragma unroll
    for (int ct = 0; ct < 16; ++ct)
#pragma unroll
        for (int nt = 0; nt < 2; ++nt) {
            int n = n_w + nt * 16 + col;
#pragma unroll
            for (int rr = 0; rr < 4; ++rr) {
                int c = ct * 16 + g16 * 4 + rr;
                ob[(size_t)c * N_ + n] = acc[ct][nt][rr] + beta_s[c];
            }
        }
}

extern "C" void kernel_launch(void* const* d_in, const int* in_sizes, int n_in,
                              void* d_out, int out_size, void* d_ws, size_t ws_size,
                              hipStream_t stream) {
    (void)in_sizes; (void)n_in; (void)out_size;
    const float* x     = (const float*)d_in[0];
    const float* Wq    = (const float*)d_in[1];
    const float* bq    = (const float*)d_in[2];
    const float* Wk    = (const float*)d_in[3];
    const float* bk    = (const float*)d_in[4];
    const float* Wv    = (const float*)d_in[5];
    const float* bv    = (const float*)d_in[6];
    const float* outer = (const float*)d_in[7];
    float* out = (float*)d_out;

    char* w = (char*)d_ws;
    float* mean   = (float*)(w + 0);
    float* rsig   = (float*)(w + 2048);
    float* beta   = (float*)(w + 4096);
    float* rspart = (float*)(w + 8192);                 // 108*2*256*4 = 221184
    float* Graw   = (float*)(w + 262144);               // 512K
    float* P      = (float*)(w + 786432);               // 512K
    float* atten  = (float*)(w + 1310720);              // 512K
    short* Abf    = (short*)(w + 1835008);              // 256K
    const size_t fixed = 2097152;                       // 2 MB
    const size_t part_bytes = (size_t)NCK_ * B_ * C_ * C_ * 4;   // 56.6 MB
    const size_t xf_bytes = (size_t)B_ * CN_ * 2;                // 113.25 MB
    float* part = (float*)(w + fixed);
    short* xf   = (short*)(w + fixed + part_bytes);

    const bool big = ws_size >= fixed + part_bytes + xf_bytes;

    k_gram  <<<dim3(NCK_, B_), 1024, 0, stream>>>(x, part, rspart, xf, big ? 1 : 0);
    k_reduce<<<dim3(B_ * C_), 256, 0, stream>>>(part, rspart, Graw, mean, rsig);
    k_gemm1 <<<dim3(B_ * C_), C_, 0, stream>>>(Wq, Graw, mean, rsig, P);
    k_attn  <<<dim3(B_ * C_), C_, 0, stream>>>(P, Wk, bq, bk, outer, atten);
    k_gemm3 <<<dim3(B_ * C_), C_, 0, stream>>>(atten, Wv, bv, mean, rsig, Abf, beta);
    if (big) {
        k_out2  <<<dim3(N_ / 256, B_), 512, 0, stream>>>(xf, Abf, beta, out);
    } else {
        k_out_f32<<<dim3(N_ / 256, B_), 512, 0, stream>>>(x, Abf, beta, out);
    }
}